// Round 3
// baseline (3013.757 us; speedup 1.0000x reference)
//
#include <hip/hip_runtime.h>

// Problem constants
#define BATCH 4
#define SEQ 4096
#define DM 1024
#define HALF_D 512             // DM/2 rope pairs
#define NROWS (BATCH * SEQ)    // 16384
#define NT128 528              // 32*33/2 lower-tri 128x128 tiles per batch
#define TILE_ELE 16384         // 128*128

typedef _Float16 f16x8 __attribute__((ext_vector_type(8)));
typedef _Float16 f16x4 __attribute__((ext_vector_type(4)));
typedef _Float16 f16x2 __attribute__((ext_vector_type(2)));
typedef float f32x4 __attribute__((ext_vector_type(4)));

#define AS1(p) ((const __attribute__((address_space(1))) void*)(p))
#define AS3(p) ((__attribute__((address_space(3))) void*)(p))

// ---------------- fp32 -> fp16 convert (8 elems/thread) ----------------
__global__ __launch_bounds__(256) void cvt_f32_f16(
    const float* __restrict__ src, _Float16* __restrict__ dst, int n8) {
  int i = blockIdx.x * 256 + threadIdx.x;
  if (i >= n8) return;
  const float4* s = (const float4*)src;
  float4 a = s[2 * i], b = s[2 * i + 1];
  f16x8 h;
  h[0] = (_Float16)a.x; h[1] = (_Float16)a.y;
  h[2] = (_Float16)a.z; h[3] = (_Float16)a.w;
  h[4] = (_Float16)b.x; h[5] = (_Float16)b.y;
  h[6] = (_Float16)b.z; h[7] = (_Float16)b.w;
  *(f16x8*)&dst[8 * i] = h;
}

// ---------------- RoPE apply in place on fp16 q or k ----------------
__global__ __launch_bounds__(256) void rope_apply(_Float16* __restrict__ T) {
  int idx = blockIdx.x * 256 + threadIdx.x;  // NROWS*HALF_D
  int row = idx >> 9;
  int i = idx & 511;
  int pos = row & (SEQ - 1);
  float theta = expf(-0.017988946039016f * ((float)i - 1.0f));  // 10000^(-2(i-1)/DM)
  float ang = (float)pos * theta;
  float c = cosf(ang), s = sinf(ang);
  f16x2 p = ((f16x2*)T)[idx];
  float e = (float)p[0], o = (float)p[1];
  p[0] = (_Float16)(e * c + o * s);
  p[1] = (_Float16)(o * c - e * s);
  ((f16x2*)T)[idx] = p;
}

// =====================================================================
// BK=32 256x256-tile NT GEMM core, 512 thr = 8 waves (2x4), 128x64/wave.
// LDS 64 KiB = 2 dbuf x (A 256x32 + B 256x32) f16 -> 2 blocks/CU.
// No swizzle needed: a wave's fragment read (16 rows x 4 chunks of 16B at
// row-stride 64B) is one contiguous 1024B block -> conflict-free linear.
// Counted vmcnt(4) depth-2 prefetch; 2 barriers per K-tile.
// =====================================================================

// ---- merged QKV projections: grid (DM/256, NROWS/256, 3) ----
// z=0: Q=X@Wq^T -> Qo ; z=1: K -> Ko ; z=2: V -> Vt[b][d][m] transposed
__global__ __launch_bounds__(512, 4) void gemm_qkv(
    const _Float16* __restrict__ X, const _Float16* __restrict__ Wq,
    const _Float16* __restrict__ Wk, const _Float16* __restrict__ Wv,
    _Float16* __restrict__ Qo, _Float16* __restrict__ Ko,
    _Float16* __restrict__ Vt) {
  const int bx = blockIdx.x, by = blockIdx.y, bz = blockIdx.z;
  const _Float16* Bw = (bz == 0) ? Wq : (bz == 1) ? Wk : Wv;

  extern __shared__ __align__(16) _Float16 lds[];  // 32768 f16 = 64 KiB

  const int tid = threadIdx.x;
  const int lane = tid & 63, wave = tid >> 6;
  const int wr = wave >> 2, wc = wave & 3;
  const int r16 = lane & 15, quad = lane >> 4;
  const int m0 = by * 256, n0 = bx * 256;

  // staging: chunk c = i*512 + tid; row = c>>2 (0..255), col = c&3 (16B)
  const _Float16* pA[2];
  const _Float16* pB[2];
#pragma unroll
  for (int i = 0; i < 2; ++i) {
    int c = i * 512 + tid;
    int row = c >> 2, col = c & 3;
    pA[i] = X + (size_t)(m0 + row) * DM + col * 8;
    pB[i] = Bw + (size_t)(n0 + row) * DM + col * 8;
  }

#define STAGE(d)                                                              \
  {                                                                           \
    _Pragma("unroll") for (int i = 0; i < 2; ++i) {                           \
      int cu = (i * 512 + wave * 64) * 8;                                     \
      __builtin_amdgcn_global_load_lds(AS1(pA[i]),                            \
                                       AS3(&lds[(d) * 16384 + cu]), 16, 0, 0);\
      __builtin_amdgcn_global_load_lds(                                       \
          AS1(pB[i]), AS3(&lds[(d) * 16384 + 8192 + cu]), 16, 0, 0);          \
    }                                                                         \
    _Pragma("unroll") for (int i = 0; i < 2; ++i) { pA[i] += 32; pB[i] += 32; }\
  }

  f32x4 acc[8][4] = {};
  const int NKT = DM / 32;  // 32

  STAGE(0);
  STAGE(1);
  asm volatile("s_waitcnt vmcnt(4)" ::: "memory");
  __builtin_amdgcn_s_barrier();

  for (int kt = 0; kt < NKT; ++kt) {
    const int d = kt & 1;
    const _Float16* Ab = lds + d * 16384 + wr * 4096;   // wr*128 rows * 32
    const _Float16* Bb = lds + d * 16384 + 8192 + wc * 2048;  // wc*64 rows
    f16x8 af[8], bf[4];
#pragma unroll
    for (int mi = 0; mi < 8; ++mi)
      af[mi] = *(const f16x8*)&Ab[(mi * 16 + r16) * 32 + quad * 8];
#pragma unroll
    for (int ni = 0; ni < 4; ++ni)
      bf[ni] = *(const f16x8*)&Bb[(ni * 16 + r16) * 32 + quad * 8];
    __builtin_amdgcn_s_setprio(1);
#pragma unroll
    for (int mi = 0; mi < 8; ++mi)
#pragma unroll
      for (int ni = 0; ni < 4; ++ni)
        acc[mi][ni] = __builtin_amdgcn_mfma_f32_16x16x32_f16(
            af[mi], bf[ni], acc[mi][ni], 0, 0, 0);
    __builtin_amdgcn_s_setprio(0);
    __builtin_amdgcn_s_barrier();  // all waves done reading dbuf[d]
    if (kt + 2 < NKT) {
      STAGE(d);
      asm volatile("s_waitcnt vmcnt(4)" ::: "memory");  // tile kt+1 landed
    } else if (kt + 1 < NKT) {
      asm volatile("s_waitcnt vmcnt(0)" ::: "memory");
    }
    __builtin_amdgcn_s_barrier();  // tile kt+1 visible
  }
#undef STAGE

  if (bz < 2) {  // row-major fp16
    _Float16* C = (bz == 0) ? Qo : Ko;
#pragma unroll
    for (int mi = 0; mi < 8; ++mi)
#pragma unroll
      for (int ni = 0; ni < 4; ++ni)
#pragma unroll
        for (int r = 0; r < 4; ++r) {
          int grow = m0 + wr * 128 + mi * 16 + quad * 4 + r;
          int gcol = n0 + wc * 64 + ni * 16 + r16;
          C[(size_t)grow * DM + gcol] = (_Float16)acc[mi][ni][r];
        }
  } else {  // Vt[b][d][m]
#pragma unroll
    for (int mi = 0; mi < 8; ++mi)
#pragma unroll
      for (int ni = 0; ni < 4; ++ni) {
        int gcol = n0 + wc * 64 + ni * 16 + r16;          // d
        int growb = m0 + wr * 128 + mi * 16 + quad * 4;   // m base
        int b = growb >> 12;
        int m = growb & (SEQ - 1);
        f16x4 t;
#pragma unroll
        for (int r = 0; r < 4; ++r) t[r] = (_Float16)acc[mi][ni][r];
        *(f16x4*)&Vt[((size_t)b * DM + gcol) * SEQ + m] = t;
      }
  }
}

// ---- scores: S = Q@K^T * 1/32, causal, packed lower-tri 128-tiles ----
__global__ __launch_bounds__(512, 4) void gemm_s(
    const _Float16* __restrict__ Q, const _Float16* __restrict__ Kh,
    _Float16* __restrict__ Sp) {
  const int bx = blockIdx.x, by = blockIdx.y, bz = blockIdx.z;
  if (bx > by) return;  // fully above diagonal (256-granular)
  const _Float16* A = Q + (size_t)bz * SEQ * DM;
  const _Float16* B = Kh + (size_t)bz * SEQ * DM;

  extern __shared__ __align__(16) _Float16 lds[];  // 64 KiB

  const int tid = threadIdx.x;
  const int lane = tid & 63, wave = tid >> 6;
  const int wr = wave >> 2, wc = wave & 3;
  const int r16 = lane & 15, quad = lane >> 4;
  const int m0 = by * 256, n0 = bx * 256;

  const _Float16* pA[2];
  const _Float16* pB[2];
#pragma unroll
  for (int i = 0; i < 2; ++i) {
    int c = i * 512 + tid;
    int row = c >> 2, col = c & 3;
    pA[i] = A + (size_t)(m0 + row) * DM + col * 8;
    pB[i] = B + (size_t)(n0 + row) * DM + col * 8;
  }

#define STAGE(d)                                                              \
  {                                                                           \
    _Pragma("unroll") for (int i = 0; i < 2; ++i) {                           \
      int cu = (i * 512 + wave * 64) * 8;                                     \
      __builtin_amdgcn_global_load_lds(AS1(pA[i]),                            \
                                       AS3(&lds[(d) * 16384 + cu]), 16, 0, 0);\
      __builtin_amdgcn_global_load_lds(                                       \
          AS1(pB[i]), AS3(&lds[(d) * 16384 + 8192 + cu]), 16, 0, 0);          \
    }                                                                         \
    _Pragma("unroll") for (int i = 0; i < 2; ++i) { pA[i] += 32; pB[i] += 32; }\
  }

  f32x4 acc[8][4] = {};
  const int NKT = DM / 32;

  STAGE(0);
  STAGE(1);
  asm volatile("s_waitcnt vmcnt(4)" ::: "memory");
  __builtin_amdgcn_s_barrier();

  for (int kt = 0; kt < NKT; ++kt) {
    const int d = kt & 1;
    const _Float16* Ab = lds + d * 16384 + wr * 4096;
    const _Float16* Bb = lds + d * 16384 + 8192 + wc * 2048;
    f16x8 af[8], bf[4];
#pragma unroll
    for (int mi = 0; mi < 8; ++mi)
      af[mi] = *(const f16x8*)&Ab[(mi * 16 + r16) * 32 + quad * 8];
#pragma unroll
    for (int ni = 0; ni < 4; ++ni)
      bf[ni] = *(const f16x8*)&Bb[(ni * 16 + r16) * 32 + quad * 8];
    __builtin_amdgcn_s_setprio(1);
#pragma unroll
    for (int mi = 0; mi < 8; ++mi)
#pragma unroll
      for (int ni = 0; ni < 4; ++ni)
        acc[mi][ni] = __builtin_amdgcn_mfma_f32_16x16x32_f16(
            af[mi], bf[ni], acc[mi][ni], 0, 0, 0);
    __builtin_amdgcn_s_setprio(0);
    __builtin_amdgcn_s_barrier();
    if (kt + 2 < NKT) {
      STAGE(d);
      asm volatile("s_waitcnt vmcnt(4)" ::: "memory");
    } else if (kt + 1 < NKT) {
      asm volatile("s_waitcnt vmcnt(0)" ::: "memory");
    }
    __builtin_amdgcn_s_barrier();
  }
#undef STAGE

  // epilogue: 128x128 quadrants into packed lower-tri layout
  int i128 = by * 2 + wr;
  int j128 = bx * 2 + (wc >> 1);
  if (j128 <= i128) {
    _Float16* T = Sp + (size_t)bz * ((size_t)NT128 * TILE_ELE) +
                  (size_t)(i128 * (i128 + 1) / 2 + j128) * TILE_ELE;
#pragma unroll
    for (int mi = 0; mi < 8; ++mi)
#pragma unroll
      for (int ni = 0; ni < 4; ++ni)
#pragma unroll
        for (int r = 0; r < 4; ++r) {
          int lr = mi * 16 + quad * 4 + r;         // 0..127
          int lc = (wc & 1) * 64 + ni * 16 + r16;  // 0..127
          T[lr * 128 + lc] = (_Float16)(acc[mi][ni][r] * 0.03125f);
        }
  }
}

// =====================================================================
// PV: O = P @ V, 128x256-tile, BK=32, 512 thr (2x4 waves, 64x64/wave).
// LDS 48 KiB = 2 dbuf x (A 128x32 + B 256x32) f16 -> 3 blocks/CU.
// A = packed lower-tri fp16 P, B = V^T [B][DM][SEQ], C fp32.
// Counted vmcnt(3) depth-2; linear LDS (conflict-free at BK=32).
// Grid 512 blocks 1D heavy-first: by = 31-(id>>4).
// =====================================================================
__global__ __launch_bounds__(512, 6) void gemm_pv(
    const _Float16* __restrict__ P, const _Float16* __restrict__ Vt,
    float* __restrict__ O) {
  const int id = blockIdx.x;
  const int by = 31 - (id >> 4);  // heavy (large K) first
  const int bx = id & 3;          // DM/256 col-tile
  const int bz = (id >> 2) & 3;   // batch

  extern __shared__ __align__(16) _Float16 lds[];  // 24576 f16 = 48 KiB

  const int tid = threadIdx.x;
  const int lane = tid & 63, wave = tid >> 6;
  const int wr = wave >> 2, wc = wave & 3;
  const int r16 = lane & 15, quad = lane >> 4;
  const int n0 = bx * 256;

  const _Float16* Pb = P + (size_t)bz * ((size_t)NT128 * TILE_ELE) +
                       (size_t)(by * (by + 1) / 2) * TILE_ELE;
  const _Float16* Vb = Vt + (size_t)bz * ((size_t)DM * SEQ) + (size_t)n0 * SEQ;

  const int NKT = (by + 1) * 4;  // BK=32 tiles, >= 4

  // stage K-tile t -> dbuf dd: A 512 chunks (1/thr), B 1024 chunks (2/thr)
#define PV_STAGE(t, dd)                                                       \
  {                                                                           \
    {                                                                         \
      int row = tid >> 2, col = tid & 3;                                      \
      const _Float16* gA = Pb + (size_t)((t) >> 2) * TILE_ELE + row * 128 +   \
                           ((t) & 3) * 32 + col * 8;                          \
      __builtin_amdgcn_global_load_lds(                                       \
          AS1(gA), AS3(&lds[(dd) * 12288 + wave * 512]), 16, 0, 0);           \
    }                                                                         \
    _Pragma("unroll") for (int i = 0; i < 2; ++i) {                           \
      int c = i * 512 + tid;                                                  \
      int row = c >> 2, col = c & 3;                                          \
      const _Float16* gB = Vb + (size_t)row * SEQ + (t) * 32 + col * 8;       \
      __builtin_amdgcn_global_load_lds(                                       \
          AS1(gB),                                                            \
          AS3(&lds[(dd) * 12288 + 4096 + (i * 512 + wave * 64) * 8]), 16, 0,  \
          0);                                                                 \
    }                                                                         \
  }

  f32x4 acc[4][4] = {};

  PV_STAGE(0, 0);
  PV_STAGE(1, 1);
  asm volatile("s_waitcnt vmcnt(3)" ::: "memory");
  __builtin_amdgcn_s_barrier();

  for (int kt = 0; kt < NKT; ++kt) {
    const int d = kt & 1;
    const _Float16* Ab = lds + d * 12288;
    const _Float16* Bb = Ab + 4096;
    f16x8 af[4], bf[4];
#pragma unroll
    for (int mi = 0; mi < 4; ++mi)
      af[mi] = *(const f16x8*)&Ab[(wr * 64 + mi * 16 + r16) * 32 + quad * 8];
#pragma unroll
    for (int ni = 0; ni < 4; ++ni)
      bf[ni] = *(const f16x8*)&Bb[(wc * 64 + ni * 16 + r16) * 32 + quad * 8];
    __builtin_amdgcn_s_setprio(1);
#pragma unroll
    for (int mi = 0; mi < 4; ++mi)
#pragma unroll
      for (int ni = 0; ni < 4; ++ni)
        acc[mi][ni] = __builtin_amdgcn_mfma_f32_16x16x32_f16(
            af[mi], bf[ni], acc[mi][ni], 0, 0, 0);
    __builtin_amdgcn_s_setprio(0);
    __builtin_amdgcn_s_barrier();  // all waves consumed dbuf[d]
    if (kt + 2 < NKT) {
      PV_STAGE(kt + 2, d);
      asm volatile("s_waitcnt vmcnt(3)" ::: "memory");  // tile kt+1 landed
    } else if (kt + 1 < NKT) {
      asm volatile("s_waitcnt vmcnt(0)" ::: "memory");
    }
    __builtin_amdgcn_s_barrier();  // tile kt+1 visible
  }
#undef PV_STAGE

  float* C = O + (size_t)bz * ((size_t)SEQ * DM);
#pragma unroll
  for (int mi = 0; mi < 4; ++mi)
#pragma unroll
    for (int ni = 0; ni < 4; ++ni)
#pragma unroll
      for (int r = 0; r < 4; ++r) {
        int grow = by * 128 + wr * 64 + mi * 16 + quad * 4 + r;
        int gcol = n0 + wc * 64 + ni * 16 + r16;
        C[(size_t)grow * DM + gcol] = acc[mi][ni][r];
      }
}

// ---------------- row softmax on packed fp16 scores, fp16 P in place ----------------
__global__ __launch_bounds__(256) void softmax_rows(_Float16* __restrict__ Sp) {
  __shared__ float vals[SEQ];
  __shared__ float red[256];
  int row = blockIdx.x;  // 0..NROWS-1
  int b = row >> 12;
  int q = row & (SEQ - 1);
  int i = q >> 7, r = q & 127;
  _Float16* base = Sp + (size_t)b * ((size_t)NT128 * TILE_ELE) +
                   (size_t)(i * (i + 1) / 2) * TILE_ELE + (size_t)r * 128;
  int tid = threadIdx.x;
  int Kv = q + 1;
  float m = -__builtin_inff();
  for (int kb = tid * 8; kb + 8 <= Kv; kb += 2048) {
    f16x8 v8 = *(const f16x8*)&base[(kb >> 7) * TILE_ELE + (kb & 127)];
#pragma unroll
    for (int t = 0; t < 8; ++t) {
      float v = (float)v8[t];
      vals[kb + t] = v;
      m = fmaxf(m, v);
    }
  }
  if (tid == 0) {
    for (int k = Kv & ~7; k < Kv; ++k) {
      float v = (float)base[(k >> 7) * TILE_ELE + (k & 127)];
      vals[k] = v;
      m = fmaxf(m, v);
    }
  }
  red[tid] = m;
  __syncthreads();
  for (int s = 128; s > 0; s >>= 1) {
    if (tid < s) red[tid] = fmaxf(red[tid], red[tid + s]);
    __syncthreads();
  }
  m = red[0];
  __syncthreads();
  float l = 0.f;
  for (int k = tid; k < Kv; k += 256) {
    float e = __expf(vals[k] - m);
    vals[k] = e;
    l += e;
  }
  red[tid] = l;
  __syncthreads();
  for (int s = 128; s > 0; s >>= 1) {
    if (tid < s) red[tid] += red[tid + s];
    __syncthreads();
  }
  float inv = 1.0f / red[0];
  int Kend = (i + 1) * 128;
  for (int kb = tid * 8; kb < Kend; kb += 2048) {
    f16x8 p;
#pragma unroll
    for (int t = 0; t < 8; ++t) {
      int k = kb + t;
      p[t] = (k < Kv) ? (_Float16)(vals[k] * inv) : (_Float16)0.f;
    }
    *(f16x8*)&base[(kb >> 7) * TILE_ELE + (kb & 127)] = p;
  }
}

extern "C" void kernel_launch(void* const* d_in, const int* in_sizes, int n_in,
                              void* d_out, int out_size, void* d_ws,
                              size_t ws_size, hipStream_t stream) {
  const float* x = (const float*)d_in[0];
  const float* wq = (const float*)d_in[1];
  const float* wk = (const float*)d_in[2];
  const float* wv = (const float*)d_in[3];

  // Workspace layout (~98 MiB), unchanged:
  //   [0, 69206016)            : Sp (packed tri fp16 scores)
  //     aliased early: xh [0,33554432) ; wqh/wkh/wvh [33554432, ...)
  //   [69206016, +33554432)    : vth (fp16 V^T, [B][DM][SEQ])
  char* ws = (char*)d_ws;
  _Float16* Sp = (_Float16*)ws;
  _Float16* xh = (_Float16*)ws;
  _Float16* wqh = (_Float16*)(ws + 33554432);
  _Float16* wkh = wqh + (size_t)DM * DM;
  _Float16* wvh = wkh + (size_t)DM * DM;
  _Float16* vth = (_Float16*)(ws + 69206016);
  _Float16* qh = (_Float16*)d_out;
  _Float16* kh = qh + (size_t)NROWS * DM;
  (void)ws_size; (void)in_sizes; (void)n_in; (void)out_size;

  static int attr_done = 0;
  if (!attr_done) {
    hipFuncSetAttribute(reinterpret_cast<const void*>(&gemm_qkv),
                        hipFuncAttributeMaxDynamicSharedMemorySize, 65536);
    hipFuncSetAttribute(reinterpret_cast<const void*>(&gemm_s),
                        hipFuncAttributeMaxDynamicSharedMemorySize, 65536);
    hipFuncSetAttribute(reinterpret_cast<const void*>(&gemm_pv),
                        hipFuncAttributeMaxDynamicSharedMemorySize, 49152);
    attr_done = 1;
  }

  // 1. fp32 -> fp16 converts
  cvt_f32_f16<<<8192, 256, 0, stream>>>(x, xh, NROWS * DM / 8);
  cvt_f32_f16<<<512, 256, 0, stream>>>(wq, wqh, DM * DM / 8);
  cvt_f32_f16<<<512, 256, 0, stream>>>(wk, wkh, DM * DM / 8);
  cvt_f32_f16<<<512, 256, 0, stream>>>(wv, wvh, DM * DM / 8);

  // 2. merged QKV projections (768 blocks, 2 blocks/CU)
  gemm_qkv<<<dim3(DM / 256, NROWS / 256, 3), 512, 65536, stream>>>(
      xh, wqh, wkh, wvh, qh, kh, vth);

  // 3. RoPE q,k in place
  rope_apply<<<NROWS * HALF_D / 256, 256, 0, stream>>>(qh);
  rope_apply<<<NROWS * HALF_D / 256, 256, 0, stream>>>(kh);

  // 4. scores (BK=32, 2 blocks/CU; epilogue -> packed lower-tri 128-tiles)
  gemm_s<<<dim3(SEQ / 256, SEQ / 256, BATCH), 512, 65536, stream>>>(qh, kh, Sp);

  // 5. softmax rows -> fp16 P in place
  softmax_rows<<<NROWS, 256, 0, stream>>>(Sp);

  // 6. O = P @ V (BK=32, 3 blocks/CU, heavy-first 1D grid)
  gemm_pv<<<512, 512, 49152, stream>>>(Sp, vth, (float*)d_out);
}

// Round 4
// 522.185 us; speedup vs baseline: 5.7714x; 5.7714x over previous
//
#include <hip/hip_runtime.h>

// Problem constants
#define BATCH 4
#define SEQ 4096
#define DM 1024
#define HALF_D 512             // DM/2 rope pairs
#define NROWS (BATCH * SEQ)    // 16384
#define NT128 528              // 32*33/2 lower-tri 128x128 tiles per batch
#define TILE_ELE 16384         // 128*128

typedef _Float16 f16x8 __attribute__((ext_vector_type(8)));
typedef _Float16 f16x4 __attribute__((ext_vector_type(4)));
typedef _Float16 f16x2 __attribute__((ext_vector_type(2)));
typedef float f32x4 __attribute__((ext_vector_type(4)));

#define AS1(p) ((const __attribute__((address_space(1))) void*)(p))
#define AS3(p) ((__attribute__((address_space(3))) void*)(p))

// ---------------- fp32 -> fp16 convert (8 elems/thread) ----------------
__global__ __launch_bounds__(256) void cvt_f32_f16(
    const float* __restrict__ src, _Float16* __restrict__ dst, int n8) {
  int i = blockIdx.x * 256 + threadIdx.x;
  if (i >= n8) return;
  const float4* s = (const float4*)src;
  float4 a = s[2 * i], b = s[2 * i + 1];
  f16x8 h;
  h[0] = (_Float16)a.x; h[1] = (_Float16)a.y;
  h[2] = (_Float16)a.z; h[3] = (_Float16)a.w;
  h[4] = (_Float16)b.x; h[5] = (_Float16)b.y;
  h[6] = (_Float16)b.z; h[7] = (_Float16)b.w;
  *(f16x8*)&dst[8 * i] = h;
}

// ---------------- RoPE apply in place on fp16 q or k ----------------
__global__ __launch_bounds__(256) void rope_apply(_Float16* __restrict__ T) {
  int idx = blockIdx.x * 256 + threadIdx.x;  // NROWS*HALF_D
  int row = idx >> 9;
  int i = idx & 511;
  int pos = row & (SEQ - 1);
  float theta = expf(-0.017988946039016f * ((float)i - 1.0f));  // 10000^(-2(i-1)/DM)
  float ang = (float)pos * theta;
  float c = cosf(ang), s = sinf(ang);
  f16x2 p = ((f16x2*)T)[idx];
  float e = (float)p[0], o = (float)p[1];
  p[0] = (_Float16)(e * c + o * s);
  p[1] = (_Float16)(o * c - e * s);
  ((f16x2*)T)[idx] = p;
}

// =====================================================================
// 256x256-tile 8-phase NT GEMM (m201-style, f16): C[m][n]=sum_k A[m][k]B[n][k]
// BK=64, 512 thr = 8 waves (2x4), 128x64/wave, LDS 128 KiB (2 dbuf).
// XOR swizzle both-sides (verified rounds 1-2, zero conflicts).
// SPREAD STAGING (m196 fine-interleave): B(kt+1) issued at phase 1 (into
// dbuf[d^1], not read during kt); A(kt+2) at phase 4 (dbuf[d], free after
// phase-3 barrier). vmcnt(4) at phase 4 drains exactly tile kt+1
// (queue: A(i+1), B(i+1), A(i+2)). Never drains to 0 in steady state.
// MODE 1: scores: scale 1/32, 128x128 quadrants -> packed lower-tri tiles
// MODE 4: merged QKV: bz selects weight/output; bz==2 writes Vt[b][d][m]
// =====================================================================
template <int MODE>
__global__ __launch_bounds__(512, 2) void gemm256(
    const _Float16* __restrict__ A, const _Float16* __restrict__ B0,
    const _Float16* __restrict__ B1, const _Float16* __restrict__ B2,
    void* __restrict__ C0, void* __restrict__ C1, void* __restrict__ C2,
    int K, int lda, int ldb, int ldc,
    long long strideA, long long strideB, long long strideC) {
  const int bx = blockIdx.x, by = blockIdx.y, bz = blockIdx.z;
  if (MODE == 1 && bx > by) return;  // fully above diagonal (256-granular)
  const _Float16* Asel = A + (size_t)bz * strideA;
  const _Float16* Bsel =
      (MODE == 4) ? (bz == 0 ? B0 : bz == 1 ? B1 : B2) : B0 + (size_t)bz * strideB;

  extern __shared__ __align__(16) _Float16 lds[];  // 65536 f16 = 128 KiB

  const int tid = threadIdx.x;
  const int lane = tid & 63, wave = tid >> 6;
  const int wr = wave >> 2, wc = wave & 3;   // wave grid 2x4
  const int r16 = lane & 15, quad = lane >> 4;
  const int m0 = by * 256, n0 = bx * 256;

  // staging: chunk c = i*512 + tid; row=c>>3 (0..127), 16B source col
  // pre-swizzled: scol = (c&7) ^ (row&7)
  const _Float16* pA[2][2];  // [half][i]
  const _Float16* pB[2][2];
#pragma unroll
  for (int i = 0; i < 2; ++i) {
    int c = i * 512 + tid;
    int row = c >> 3;
    int scol = (c & 7) ^ (row & 7);
#pragma unroll
    for (int h = 0; h < 2; ++h) {
      pA[h][i] = Asel + (size_t)(m0 + h * 128 + row) * lda + scol * 8;
      pB[h][i] = Bsel + (size_t)(n0 + h * 128 + row) * ldb + scol * 8;
    }
  }

#define STAGE_A(d)                                                           \
  {                                                                          \
    _Pragma("unroll") for (int i = 0; i < 2; ++i) {                          \
      int cu = (i * 512 + wave * 64) * 8;                                    \
      _Pragma("unroll") for (int h = 0; h < 2; ++h) {                        \
        __builtin_amdgcn_global_load_lds(                                    \
            AS1(pA[h][i]), AS3(&lds[((d) * 4 + h) * 8192 + cu]), 16, 0, 0);  \
        pA[h][i] += 64;                                                      \
      }                                                                      \
    }                                                                        \
  }
#define STAGE_B(d)                                                           \
  {                                                                          \
    _Pragma("unroll") for (int i = 0; i < 2; ++i) {                          \
      int cu = (i * 512 + wave * 64) * 8;                                    \
      _Pragma("unroll") for (int h = 0; h < 2; ++h) {                        \
        __builtin_amdgcn_global_load_lds(                                    \
            AS1(pB[h][i]), AS3(&lds[((d) * 4 + 2 + h) * 8192 + cu]), 16, 0,  \
            0);                                                              \
        pB[h][i] += 64;                                                      \
      }                                                                      \
    }                                                                        \
  }

  f32x4 acc[8][4] = {};

  const int NKT = K >> 6;  // BK=64 K-tiles (16 here)

  // swizzled ds_read col offsets (elems) for k-halves 0/1
  const int aoff0 = ((quad) ^ (r16 & 7)) * 8;
  const int aoff1 = ((4 + quad) ^ (r16 & 7)) * 8;

  // prologue: A0,B0,A1 issued; wait tile0 (A1 stays in flight)
  STAGE_A(0);
  STAGE_B(0);
  STAGE_A(1);
  asm volatile("s_waitcnt vmcnt(4)" ::: "memory");
  __builtin_amdgcn_s_barrier();

  for (int kt = 0; kt < NKT; ++kt) {
    const int d = kt & 1;
    const _Float16* Ab = lds + (d * 4 + wr) * 8192;
    const _Float16* Bb = lds + (d * 4 + 2 + (wc >> 1)) * 8192 + (wc & 1) * 4096;
    f16x8 af[4][2], bf[4][2];

    // phase 1: issue B(kt+1) -> dbuf[d^1]; read af(mi0-3)+bf(ni0-1); MFMA G0
    if (kt + 1 < NKT) STAGE_B(d ^ 1);
#pragma unroll
    for (int mi = 0; mi < 4; ++mi) {
      af[mi][0] = *(const f16x8*)&Ab[(mi * 16 + r16) * 64 + aoff0];
      af[mi][1] = *(const f16x8*)&Ab[(mi * 16 + r16) * 64 + aoff1];
    }
#pragma unroll
    for (int ni = 0; ni < 2; ++ni) {
      bf[ni][0] = *(const f16x8*)&Bb[(ni * 16 + r16) * 64 + aoff0];
      bf[ni][1] = *(const f16x8*)&Bb[(ni * 16 + r16) * 64 + aoff1];
    }
    __builtin_amdgcn_s_barrier();
    __builtin_amdgcn_s_setprio(1);
#pragma unroll
    for (int mi = 0; mi < 4; ++mi)
#pragma unroll
      for (int ni = 0; ni < 2; ++ni) {
        acc[mi][ni] = __builtin_amdgcn_mfma_f32_16x16x32_f16(
            af[mi][0], bf[ni][0], acc[mi][ni], 0, 0, 0);
        acc[mi][ni] = __builtin_amdgcn_mfma_f32_16x16x32_f16(
            af[mi][1], bf[ni][1], acc[mi][ni], 0, 0, 0);
      }
    __builtin_amdgcn_s_setprio(0);
    __builtin_amdgcn_s_barrier();

    // phase 2: read bf(ni2-3); MFMA G1
#pragma unroll
    for (int ni = 2; ni < 4; ++ni) {
      bf[ni][0] = *(const f16x8*)&Bb[(ni * 16 + r16) * 64 + aoff0];
      bf[ni][1] = *(const f16x8*)&Bb[(ni * 16 + r16) * 64 + aoff1];
    }
    __builtin_amdgcn_s_barrier();
    __builtin_amdgcn_s_setprio(1);
#pragma unroll
    for (int mi = 0; mi < 4; ++mi)
#pragma unroll
      for (int ni = 2; ni < 4; ++ni) {
        acc[mi][ni] = __builtin_amdgcn_mfma_f32_16x16x32_f16(
            af[mi][0], bf[ni][0], acc[mi][ni], 0, 0, 0);
        acc[mi][ni] = __builtin_amdgcn_mfma_f32_16x16x32_f16(
            af[mi][1], bf[ni][1], acc[mi][ni], 0, 0, 0);
      }
    __builtin_amdgcn_s_setprio(0);
    __builtin_amdgcn_s_barrier();

    // phase 3: read af(mi4-7); MFMA G2
#pragma unroll
    for (int mi = 0; mi < 4; ++mi) {
      af[mi][0] = *(const f16x8*)&Ab[((mi + 4) * 16 + r16) * 64 + aoff0];
      af[mi][1] = *(const f16x8*)&Ab[((mi + 4) * 16 + r16) * 64 + aoff1];
    }
    __builtin_amdgcn_s_barrier();
    __builtin_amdgcn_s_setprio(1);
#pragma unroll
    for (int mi = 0; mi < 4; ++mi)
#pragma unroll
      for (int ni = 0; ni < 2; ++ni) {
        acc[mi + 4][ni] = __builtin_amdgcn_mfma_f32_16x16x32_f16(
            af[mi][0], bf[ni][0], acc[mi + 4][ni], 0, 0, 0);
        acc[mi + 4][ni] = __builtin_amdgcn_mfma_f32_16x16x32_f16(
            af[mi][1], bf[ni][1], acc[mi + 4][ni], 0, 0, 0);
      }
    __builtin_amdgcn_s_setprio(0);
    __builtin_amdgcn_s_barrier();
    // all waves' reads of dbuf[d] complete (drained through G2's operands)

    // phase 4: issue A(kt+2) -> dbuf[d]; MFMA G3; counted wait
    if (kt + 2 < NKT) STAGE_A(d);
    __builtin_amdgcn_s_setprio(1);
#pragma unroll
    for (int mi = 0; mi < 4; ++mi)
#pragma unroll
      for (int ni = 2; ni < 4; ++ni) {
        acc[mi + 4][ni] = __builtin_amdgcn_mfma_f32_16x16x32_f16(
            af[mi][0], bf[ni][0], acc[mi + 4][ni], 0, 0, 0);
        acc[mi + 4][ni] = __builtin_amdgcn_mfma_f32_16x16x32_f16(
            af[mi][1], bf[ni][1], acc[mi + 4][ni], 0, 0, 0);
      }
    __builtin_amdgcn_s_setprio(0);
    if (kt + 2 < NKT) {
      asm volatile("s_waitcnt vmcnt(4)" ::: "memory");  // tile kt+1 landed
    } else if (kt + 1 < NKT) {
      asm volatile("s_waitcnt vmcnt(0)" ::: "memory");
    }
    __builtin_amdgcn_s_barrier();
  }
#undef STAGE_A
#undef STAGE_B

  // ---- epilogues ----
  if (MODE == 4 && bz < 2) {  // Q/K row-major fp16
    _Float16* C = (_Float16*)(bz == 0 ? C0 : C1);
#pragma unroll
    for (int mi = 0; mi < 8; ++mi)
#pragma unroll
      for (int ni = 0; ni < 4; ++ni)
#pragma unroll
        for (int r = 0; r < 4; ++r) {
          int grow = m0 + wr * 128 + mi * 16 + quad * 4 + r;
          int gcol = n0 + wc * 64 + ni * 16 + r16;
          C[(size_t)grow * ldc + gcol] = (_Float16)acc[mi][ni][r];
        }
  } else if (MODE == 4) {  // V -> Vt[b][d][m]
    _Float16* C = (_Float16*)C2;
#pragma unroll
    for (int mi = 0; mi < 8; ++mi)
#pragma unroll
      for (int ni = 0; ni < 4; ++ni) {
        int gcol = n0 + wc * 64 + ni * 16 + r16;          // d
        int growb = m0 + wr * 128 + mi * 16 + quad * 4;   // m base
        int b = growb >> 12;
        int m = growb & (SEQ - 1);
        f16x4 t;
#pragma unroll
        for (int r = 0; r < 4; ++r) t[r] = (_Float16)acc[mi][ni][r];
        *(f16x4*)&C[((size_t)b * DM + gcol) * SEQ + m] = t;
      }
  } else {  // MODE 1: 128x128 quadrants into packed lower-tri layout
    int i128 = by * 2 + wr;
    int j128 = bx * 2 + (wc >> 1);
    if (j128 <= i128) {
      _Float16* T = (_Float16*)C0 + (size_t)bz * strideC +
                    (size_t)(i128 * (i128 + 1) / 2 + j128) * TILE_ELE;
#pragma unroll
      for (int mi = 0; mi < 8; ++mi)
#pragma unroll
        for (int ni = 0; ni < 4; ++ni)
#pragma unroll
          for (int r = 0; r < 4; ++r) {
            int lr = mi * 16 + quad * 4 + r;          // 0..127
            int lc = (wc & 1) * 64 + ni * 16 + r16;   // 0..127
            T[lr * 128 + lc] = (_Float16)(acc[mi][ni][r] * 0.03125f);
          }
    }
  }
}

// =====================================================================
// PV: O = P @ V, 128x256-tile NT GEMM, BK=64, 8 waves (2x4), 64x64/wave.
// A = packed lower-tri fp16 P (exact causal K=(by+1)*128), B = V^T, C fp32.
// LDS 96 KiB (2 dbuf), XOR-swizzled. Stage of kt+2 issued BEFORE MFMA G1
// (dbuf[d] free after the lgkmcnt(0)+barrier following G0 — all 16 ds_reads
// of dbuf[d] drained, incl. bf[2..3] consumed only in G1). vmcnt(6) counted.
// Grid 512 1D heavy-first (descending K = LPT greedy balance).
// =====================================================================
__global__ __launch_bounds__(512, 1) void gemm_pv(
    const _Float16* __restrict__ P, const _Float16* __restrict__ Vt,
    float* __restrict__ O) {
  const int id = blockIdx.x;
  const int by = 31 - (id >> 4);  // heavy (large K) first
  const int bx = id & 3;          // DM/256 col-tile
  const int bz = (id >> 2) & 3;   // batch

  extern __shared__ __align__(16) _Float16 lds[];  // 49152 f16 = 96 KiB

  const int tid = threadIdx.x;
  const int lane = tid & 63, wave = tid >> 6;
  const int wr = wave >> 2, wc = wave & 3;
  const int r16 = lane & 15, quad = lane >> 4;
  const int n0 = bx * 256;

  const _Float16* Pb = P + (size_t)bz * ((size_t)NT128 * TILE_ELE) +
                       (size_t)(by * (by + 1) / 2) * TILE_ELE;
  const _Float16* Vb = Vt + (size_t)bz * ((size_t)DM * SEQ) + (size_t)n0 * SEQ;

  const int NKT = (by + 1) * 2;  // even, >= 2

  // stage K-tile t -> dbuf dd: A 1024 chunks (2/thr), B 2048 chunks (4/thr)
#define PV_STAGE(t, dd)                                                      \
  {                                                                          \
    _Pragma("unroll") for (int i = 0; i < 2; ++i) {                          \
      int c = i * 512 + tid;                                                 \
      int row = c >> 3;                                                      \
      int scol = (c & 7) ^ (row & 7);                                        \
      const _Float16* gA = Pb + (size_t)((t) >> 1) * TILE_ELE + row * 128 +  \
                           ((t) & 1) * 64 + scol * 8;                        \
      __builtin_amdgcn_global_load_lds(                                      \
          AS1(gA), AS3(&lds[(dd) * 24576 + (i * 512 + wave * 64) * 8]), 16,  \
          0, 0);                                                             \
    }                                                                        \
    _Pragma("unroll") for (int i = 0; i < 4; ++i) {                          \
      int c = i * 512 + tid;                                                 \
      int row = c >> 3;                                                      \
      int scol = (c & 7) ^ (row & 7);                                        \
      const _Float16* gB = Vb + (size_t)row * SEQ + (t) * 64 + scol * 8;     \
      __builtin_amdgcn_global_load_lds(                                      \
          AS1(gB),                                                           \
          AS3(&lds[(dd) * 24576 + 8192 + (i * 512 + wave * 64) * 8]), 16, 0, \
          0);                                                                \
    }                                                                        \
  }

  f32x4 acc[4][4] = {};

  const int aoff0 = ((quad) ^ (r16 & 7)) * 8;
  const int aoff1 = ((4 + quad) ^ (r16 & 7)) * 8;
  const int arow = (wr * 64 + r16) * 64;
  const int brow = (wc * 64 + r16) * 64;

  // prologue: tiles 0,1 in flight; wait tile 0
  PV_STAGE(0, 0);
  PV_STAGE(1, 1);
  asm volatile("s_waitcnt vmcnt(6)" ::: "memory");
  __builtin_amdgcn_s_barrier();

  for (int kt = 0; kt < NKT; ++kt) {
    const int d = kt & 1;
    const _Float16* Ab = lds + d * 24576;
    const _Float16* Bb = Ab + 8192;
    f16x8 af[4][2], bf[4][2];

    // ---- phase A: all 16 ds_reads; MFMA G0 (ni 0-1) ----
#pragma unroll
    for (int mi = 0; mi < 4; ++mi) {
      af[mi][0] = *(const f16x8*)&Ab[arow + mi * 16 * 64 + aoff0];
      af[mi][1] = *(const f16x8*)&Ab[arow + mi * 16 * 64 + aoff1];
    }
#pragma unroll
    for (int ni = 0; ni < 4; ++ni) {
      bf[ni][0] = *(const f16x8*)&Bb[brow + ni * 16 * 64 + aoff0];
      bf[ni][1] = *(const f16x8*)&Bb[brow + ni * 16 * 64 + aoff1];
    }
    __builtin_amdgcn_s_barrier();
    __builtin_amdgcn_s_setprio(1);
#pragma unroll
    for (int mi = 0; mi < 4; ++mi)
#pragma unroll
      for (int ni = 0; ni < 2; ++ni) {
        acc[mi][ni] = __builtin_amdgcn_mfma_f32_16x16x32_f16(
            af[mi][0], bf[ni][0], acc[mi][ni], 0, 0, 0);
        acc[mi][ni] = __builtin_amdgcn_mfma_f32_16x16x32_f16(
            af[mi][1], bf[ni][1], acc[mi][ni], 0, 0, 0);
      }
    __builtin_amdgcn_s_setprio(0);
    // ensure bf[2..3] ds_reads (consumed only in G1) are drained before
    // declaring dbuf[d] free for the incoming DMA
    asm volatile("s_waitcnt lgkmcnt(0)" ::: "memory");
    __builtin_amdgcn_s_barrier();  // all waves fully done reading dbuf[d]

    // ---- phase B: issue stage kt+2 -> dbuf[d]; MFMA G1; counted wait ----
    if (kt + 2 < NKT) PV_STAGE(kt + 2, d);
    __builtin_amdgcn_s_setprio(1);
#pragma unroll
    for (int mi = 0; mi < 4; ++mi)
#pragma unroll
      for (int ni = 2; ni < 4; ++ni) {
        acc[mi][ni] = __builtin_amdgcn_mfma_f32_16x16x32_f16(
            af[mi][0], bf[ni][0], acc[mi][ni], 0, 0, 0);
        acc[mi][ni] = __builtin_amdgcn_mfma_f32_16x16x32_f16(
            af[mi][1], bf[ni][1], acc[mi][ni], 0, 0, 0);
      }
    __builtin_amdgcn_s_setprio(0);
    if (kt + 2 < NKT) {
      asm volatile("s_waitcnt vmcnt(6)" ::: "memory");  // tile kt+1 landed
    } else if (kt + 1 < NKT) {
      asm volatile("s_waitcnt vmcnt(0)" ::: "memory");
    }
    __builtin_amdgcn_s_barrier();  // tile kt+1 visible to all waves
  }
#undef PV_STAGE

  // ---- epilogue: fp32 C[b][m][d] ----
  float* C = O + (size_t)bz * ((size_t)SEQ * DM);
#pragma unroll
  for (int mi = 0; mi < 4; ++mi)
#pragma unroll
    for (int ni = 0; ni < 4; ++ni)
#pragma unroll
      for (int r = 0; r < 4; ++r) {
        int grow = by * 128 + wr * 64 + mi * 16 + quad * 4 + r;
        int gcol = n0 + wc * 64 + ni * 16 + r16;
        C[(size_t)grow * DM + gcol] = acc[mi][ni][r];
      }
}

// ---------------- row softmax on packed fp16 scores, fp16 P in place ----------------
__global__ __launch_bounds__(256) void softmax_rows(_Float16* __restrict__ Sp) {
  __shared__ float vals[SEQ];
  __shared__ float red[256];
  int row = blockIdx.x;  // 0..NROWS-1
  int b = row >> 12;
  int q = row & (SEQ - 1);
  int i = q >> 7, r = q & 127;
  _Float16* base = Sp + (size_t)b * ((size_t)NT128 * TILE_ELE) +
                   (size_t)(i * (i + 1) / 2) * TILE_ELE + (size_t)r * 128;
  int tid = threadIdx.x;
  int Kv = q + 1;
  float m = -__builtin_inff();
  for (int kb = tid * 8; kb + 8 <= Kv; kb += 2048) {
    f16x8 v8 = *(const f16x8*)&base[(kb >> 7) * TILE_ELE + (kb & 127)];
#pragma unroll
    for (int t = 0; t < 8; ++t) {
      float v = (float)v8[t];
      vals[kb + t] = v;
      m = fmaxf(m, v);
    }
  }
  if (tid == 0) {
    for (int k = Kv & ~7; k < Kv; ++k) {
      float v = (float)base[(k >> 7) * TILE_ELE + (k & 127)];
      vals[k] = v;
      m = fmaxf(m, v);
    }
  }
  red[tid] = m;
  __syncthreads();
  for (int s = 128; s > 0; s >>= 1) {
    if (tid < s) red[tid] = fmaxf(red[tid], red[tid + s]);
    __syncthreads();
  }
  m = red[0];
  __syncthreads();
  float l = 0.f;
  for (int k = tid; k < Kv; k += 256) {
    float e = __expf(vals[k] - m);
    vals[k] = e;
    l += e;
  }
  red[tid] = l;
  __syncthreads();
  for (int s = 128; s > 0; s >>= 1) {
    if (tid < s) red[tid] += red[tid + s];
    __syncthreads();
  }
  float inv = 1.0f / red[0];
  int Kend = (i + 1) * 128;  // zero-fill to tile boundary (covers PV K-extent)
  for (int kb = tid * 8; kb < Kend; kb += 2048) {
    f16x8 p;
#pragma unroll
    for (int t = 0; t < 8; ++t) {
      int k = kb + t;
      p[t] = (k < Kv) ? (_Float16)(vals[k] * inv) : (_Float16)0.f;
    }
    *(f16x8*)&base[(kb >> 7) * TILE_ELE + (kb & 127)] = p;
  }
}

extern "C" void kernel_launch(void* const* d_in, const int* in_sizes, int n_in,
                              void* d_out, int out_size, void* d_ws,
                              size_t ws_size, hipStream_t stream) {
  const float* x = (const float*)d_in[0];
  const float* wq = (const float*)d_in[1];
  const float* wk = (const float*)d_in[2];
  const float* wv = (const float*)d_in[3];

  // Workspace layout (~98 MiB):
  //   [0, 69206016)            : Sp (packed tri fp16 scores)
  //     aliased early: xh [0,33554432) ; wqh/wkh/wvh [33554432, ...)
  //   [69206016, +33554432)    : vth (fp16 V^T, [B][DM][SEQ])
  char* ws = (char*)d_ws;
  _Float16* Sp = (_Float16*)ws;
  _Float16* xh = (_Float16*)ws;
  _Float16* wqh = (_Float16*)(ws + 33554432);
  _Float16* wkh = wqh + (size_t)DM * DM;
  _Float16* wvh = wkh + (size_t)DM * DM;
  _Float16* vth = (_Float16*)(ws + 69206016);
  _Float16* qh = (_Float16*)d_out;
  _Float16* kh = qh + (size_t)NROWS * DM;
  (void)ws_size; (void)in_sizes; (void)n_in; (void)out_size;

  static int attr_done = 0;
  if (!attr_done) {
    hipFuncSetAttribute(reinterpret_cast<const void*>(&gemm256<1>),
                        hipFuncAttributeMaxDynamicSharedMemorySize, 131072);
    hipFuncSetAttribute(reinterpret_cast<const void*>(&gemm256<4>),
                        hipFuncAttributeMaxDynamicSharedMemorySize, 131072);
    hipFuncSetAttribute(reinterpret_cast<const void*>(&gemm_pv),
                        hipFuncAttributeMaxDynamicSharedMemorySize, 98304);
    attr_done = 1;
  }

  // 1. fp32 -> fp16 converts
  cvt_f32_f16<<<8192, 256, 0, stream>>>(x, xh, NROWS * DM / 8);
  cvt_f32_f16<<<512, 256, 0, stream>>>(wq, wqh, DM * DM / 8);
  cvt_f32_f16<<<512, 256, 0, stream>>>(wk, wkh, DM * DM / 8);
  cvt_f32_f16<<<512, 256, 0, stream>>>(wv, wvh, DM * DM / 8);

  // 2. merged QKV projections (768 blocks; z selects weight/output)
  gemm256<4><<<dim3(DM / 256, NROWS / 256, 3), 512, 131072, stream>>>(
      xh, wqh, wkh, wvh, qh, kh, vth, DM, DM, DM, DM, 0, 0, 0);

  // 3. RoPE q,k in place
  rope_apply<<<NROWS * HALF_D / 256, 256, 0, stream>>>(qh);
  rope_apply<<<NROWS * HALF_D / 256, 256, 0, stream>>>(kh);

  // 4. scores (spread-staged 8-phase; epilogue -> packed lower-tri tiles)
  gemm256<1><<<dim3(SEQ / 256, SEQ / 256, BATCH), 512, 131072, stream>>>(
      qh, kh, nullptr, nullptr, Sp, nullptr, nullptr, DM, DM, DM, 128,
      (long long)SEQ * DM, (long long)SEQ * DM, (long long)NT128 * TILE_ELE);

  // 5. softmax rows -> fp16 P in place
  softmax_rows<<<NROWS, 256, 0, stream>>>(Sp);

  // 6. O = P @ V (spread-staged, heavy-first 1D grid, 512 blocks)
  gemm_pv<<<512, 512, 98304, stream>>>(Sp, vth, (float*)d_out);
}